// Round 1
// baseline (1459.495 us; speedup 1.0000x reference)
//
#include <hip/hip_runtime.h>
#include <cstddef>

#define NB   32
#define CTXD 1024
#define FFD  8192
#define HD   256
#define WD   256
#define NPIX 65536
#define EPSF 1e-12f

// ---------- helpers ----------

__device__ __forceinline__ float ftanh(float x){
  // tanh(x) = sign(x) * (1 - 2/(exp(2|x|)+1)); exp overflow -> inf -> 1. ~1e-6 rel err.
  float ax = fabsf(x);
  float e  = __expf(2.0f*ax);
  float r  = 1.0f - 2.0f*__builtin_amdgcn_rcpf(e + 1.0f);
  return copysignf(r, x);
}

// reduce 4 values across a 256-thread block (4 waves of 64)
__device__ __forceinline__ void block_reduce4(float& a, float& b, float& c, float& d){
  for (int off = 32; off > 0; off >>= 1){
    a += __shfl_down(a, off); b += __shfl_down(b, off);
    c += __shfl_down(c, off); d += __shfl_down(d, off);
  }
  __shared__ float lds[16];
  int wid = threadIdx.x >> 6, lane = threadIdx.x & 63;
  if (lane == 0){ lds[wid*4+0]=a; lds[wid*4+1]=b; lds[wid*4+2]=c; lds[wid*4+3]=d; }
  __syncthreads();
  a = (lds[0]+lds[4])+(lds[8]+lds[12]);
  b = (lds[1]+lds[5])+(lds[9]+lds[13]);
  c = (lds[2]+lds[6])+(lds[10]+lds[14]);
  d = (lds[3]+lds[7])+(lds[11]+lds[15]);
}

// ---------- kernels ----------

__global__ __launch_bounds__(64) void k_init(float* __restrict__ red){
  if (threadIdx.x < 64) red[threadIdx.x] = 0.0f;   // max_s[32], max_p[32]
}

// xt = x@W_in^T + b_in ; xg = x@W_gate^T + b_gate   (stored transposed [f][b])
__global__ __launch_bounds__(256) void k_gemm1(
    const float* __restrict__ x, const float* __restrict__ Win, const float* __restrict__ bin,
    const float* __restrict__ Wg, const float* __restrict__ bg,
    float* __restrict__ xtT, float* __restrict__ xgT){
  int g   = blockIdx.x*256 + threadIdx.x;          // 524288 total
  int m   = g >> 18;
  int idx = g & 262143;
  int f = idx >> 5, b = idx & 31;
  const float4* wrow = (const float4*)((m ? Wg : Win) + (size_t)f*CTXD);
  const float4* xrow = (const float4*)(x + (size_t)b*CTXD);
  float a0=0.f,a1=0.f,a2=0.f,a3=0.f;
  #pragma unroll 8
  for (int k = 0; k < CTXD/4; ++k){
    float4 w = wrow[k], c = xrow[k];
    a0 += w.x*c.x; a1 += w.y*c.y; a2 += w.z*c.z; a3 += w.w*c.w;
  }
  float acc = (a0+a1)+(a2+a3) + (m ? bg[f] : bin[f]);
  (m ? xgT : xtT)[f*NB + b] = acc;
}

// norm over 2048-groups (ddof=1) for xt,xg; ctx_in = nt * tanh(ng)   [B][FF]
__global__ __launch_bounds__(256) void k_normgate(
    const float* __restrict__ xtT, const float* __restrict__ xgT, float* __restrict__ ctx_in){
  int b = blockIdx.x >> 2, g = blockIdx.x & 3;
  int t = threadIdx.x;
  int fbase = g*2048;
  float vt[8], vg[8];
  float st=0.f, sst=0.f, sg=0.f, ssg=0.f;
  #pragma unroll
  for (int i = 0; i < 8; ++i){
    int f = fbase + i*256 + t;
    float a = xtT[f*NB + b];
    float c = xgT[f*NB + b];
    vt[i]=a; vg[i]=c;
    st += a; sst += a*a; sg += c; ssg += c*c;
  }
  block_reduce4(st, sst, sg, ssg);
  float mt = st * (1.0f/2048.0f);
  float it = rsqrtf((sst - st*mt) * (1.0f/2047.0f) + EPSF);
  float mg = sg * (1.0f/2048.0f);
  float ig = rsqrtf((ssg - sg*mg) * (1.0f/2047.0f) + EPSF);
  #pragma unroll
  for (int i = 0; i < 8; ++i){
    int f = fbase + i*256 + t;
    float nt = (vt[i]-mt)*it;
    float ng = (vg[i]-mg)*ig;
    ctx_in[b*FFD + f] = nt * ftanh(ng);
  }
}

// ctx2 = ctx_in @ W_t^T + b_t   (stored transposed [f][b])
__global__ __launch_bounds__(256) void k_gemm2(
    const float* __restrict__ ctx_in, const float* __restrict__ Wt,
    const float* __restrict__ bt, float* __restrict__ ctx2T){
  int g = blockIdx.x*256 + threadIdx.x;            // 262144 total
  int f = g >> 5, b = g & 31;
  const float4* wrow = (const float4*)(Wt + (size_t)f*FFD);
  const float4* crow = (const float4*)(ctx_in + (size_t)b*FFD);
  float a0=0.f,a1=0.f,a2=0.f,a3=0.f;
  #pragma unroll 4
  for (int k = 0; k < FFD/4; ++k){
    float4 w = wrow[k], c = crow[k];
    a0 += w.x*c.x; a1 += w.y*c.y; a2 += w.z*c.z; a3 += w.w*c.w;
  }
  ctx2T[f*NB + b] = (a0+a1)+(a2+a3) + bt[f];
}

// norm over 512-groups (ddof=1) -> modc [B][16][512]
__global__ __launch_bounds__(256) void k_norm512(
    const float* __restrict__ ctx2T, float* __restrict__ modc){
  int b = blockIdx.x >> 4, kr = blockIdx.x & 15;
  int t = threadIdx.x;
  int base = kr*512;
  float v0 = ctx2T[(base + t      )*NB + b];
  float v1 = ctx2T[(base + 256 + t)*NB + b];
  float s = v0+v1, ss = v0*v0 + v1*v1, d0=0.f, d1=0.f;
  block_reduce4(s, ss, d0, d1);
  float m   = s * (1.0f/512.0f);
  float inv = rsqrtf((ss - s*m) * (1.0f/511.0f) + EPSF);
  modc[b*FFD + base + t      ] = (v0-m)*inv;
  modc[b*FFD + base + 256 + t] = (v1-m)*inv;
}

// pixel pass 1: outer-product tanh sums, channel mix, store planes + per-batch max
__global__ __launch_bounds__(256) void k_pixel1(
    const float* __restrict__ modc,
    const float* __restrict__ convw, const float* __restrict__ convb,
    const float* __restrict__ wmod, const float* __restrict__ wstat,
    float* __restrict__ msr, float* __restrict__ msi,
    float* __restrict__ ppr, float* __restrict__ ppi,
    float* __restrict__ red){
  int b = blockIdx.x >> 4, chunk = blockIdx.x & 15;
  int t = threadIdx.x;
  __shared__ float lds[16*512];
  #pragma unroll
  for (int i = 0; i < 8; ++i){
    float4 v = *(const float4*)(modc + (size_t)b*FFD + (i*256 + t)*4);
    *(float4*)(lds + (i*256 + t)*4) = v;
  }
  float cw0 = convw[0]+convw[4]+convw[8]+convw[12];
  float cw1 = convw[1]+convw[5]+convw[9]+convw[13];
  float cw2 = convw[2]+convw[6]+convw[10]+convw[14];
  float cw3 = convw[3]+convw[7]+convw[11]+convw[15];
  float cb  = convb[0]+convb[1]+convb[2]+convb[3];
  __syncthreads();
  int w = t;
  float mxs = 0.f, mxp = 0.f;
  for (int it = 0; it < 16; ++it){
    int h = chunk*16 + it;
    int pix = h*WD + w;
    float sk[4];
    #pragma unroll
    for (int k = 0; k < 4; ++k){
      float acc = 0.f;
      #pragma unroll
      for (int r = 0; r < 4; ++r){
        int kr = k*4 + r;
        float u  = lds[kr*512 + h];
        float vv = lds[kr*512 + 256 + w];
        float tt = ftanh(u*vv);
        float cwr = (r==0)?cw0:(r==1)?cw1:(r==2)?cw2:cw3;
        acc += (k==0) ? cwr*tt : tt;
      }
      sk[k] = acc;
    }
    sk[0] += cb;
    float m0 = sk[0]*wmod[0*NPIX+pix];
    float m1 = sk[1]*wmod[1*NPIX+pix];
    float m2 = sk[2]*wmod[2*NPIX+pix];
    float m3 = sk[3]*wmod[3*NPIX+pix];
    float2 A1 = *(const float2*)(wstat + (size_t)(NPIX + pix)*2);
    float r_ = A1.x*m0 - A1.y*m1;
    float i_ = A1.x*m1 - A1.y*m0;
    size_t o = (size_t)b*NPIX + pix;
    msr[o]=r_; msi[o]=i_; ppr[o]=m2; ppi[o]=m3;
    float as = sqrtf(r_*r_ + i_*i_ + EPSF);
    float ap = sqrtf(m2*m2 + m3*m3 + EPSF);
    mxs = fmaxf(mxs, as); mxp = fmaxf(mxp, ap);
  }
  for (int off = 32; off > 0; off >>= 1){
    mxs = fmaxf(mxs, __shfl_down(mxs, off));
    mxp = fmaxf(mxp, __shfl_down(mxp, off));
  }
  __shared__ float lred[8];
  int wid = t >> 6, lane = t & 63;
  if (lane == 0){ lred[wid] = mxs; lred[4+wid] = mxp; }
  __syncthreads();
  if (t == 0){
    float a = fmaxf(fmaxf(lred[0],lred[1]), fmaxf(lred[2],lred[3]));
    float p = fmaxf(fmaxf(lred[4],lred[5]), fmaxf(lred[6],lred[7]));
    atomicMax((int*)&red[b],      __float_as_int(a));   // values >= 0: int compare == float compare
    atomicMax((int*)&red[32+b],   __float_as_int(p));
  }
}

// pixel pass 2: deterministic partial sums of |mod_scaled| per (b, chunk)
__global__ __launch_bounds__(256) void k_magsum(
    const float* __restrict__ msr, const float* __restrict__ msi,
    const float* __restrict__ red, float* __restrict__ magpart){
  int b = blockIdx.x >> 5, chunk = blockIdx.x & 31;
  int t = threadIdx.x;
  float maxs = red[b];
  float sum = 0.f;
  #pragma unroll
  for (int i = 0; i < 8; ++i){
    int pix = chunk*2048 + i*256 + t;
    size_t o = (size_t)b*NPIX + pix;
    float r_ = msr[o], i_ = msi[o];
    float sq = r_*r_ + i_*i_;
    float as = sqrtf(sq + EPSF);
    float hs = as/(maxs + EPSF);
    float tt = hs/(as + EPSF);
    sum += sqrtf(tt*tt*sq + EPSF);
  }
  for (int off = 32; off > 0; off >>= 1) sum += __shfl_down(sum, off);
  __shared__ float lr[4];
  int wid = t >> 6, lane = t & 63;
  if (lane == 0) lr[wid] = sum;
  __syncthreads();
  if (t == 0) magpart[b*32 + chunk] = (lr[0]+lr[1])+(lr[2]+lr[3]);
}

__global__ __launch_bounds__(64) void k_finalize(
    const float* __restrict__ magpart, float* __restrict__ invmag){
  int b = threadIdx.x;
  if (b < 32){
    float s = 0.f;
    for (int i = 0; i < 32; ++i) s += magpart[b*32 + i];
    invmag[b] = 1.0f / sqrtf(s*(1.0f/65536.0f) + EPSF);
  }
}

// final: mod_weights = A0 + mod_scaled/mag ; theta from mod_proj polar ; combine
__global__ __launch_bounds__(256) void k_final(
    const float* __restrict__ msr, const float* __restrict__ msi,
    const float* __restrict__ ppr, const float* __restrict__ ppi,
    const float* __restrict__ wstat, const float* __restrict__ red,
    const float* __restrict__ invmag, float* __restrict__ out){
  int g = blockIdx.x*256 + threadIdx.x;            // 2097152 total
  int b = g >> 16, pix = g & (NPIX-1);
  size_t o = (size_t)b*NPIX + pix;
  float maxs = red[b], maxp = red[32+b], im = invmag[b];
  float r_ = msr[o], i_ = msi[o], p_ = ppr[o], q_ = ppi[o];
  float as = sqrtf(r_*r_ + i_*i_ + EPSF);
  float fs = (as/(maxs+EPSF))/(as+EPSF)*im;
  float2 A0 = *(const float2*)(wstat + (size_t)pix*2);
  float mwr = A0.x + fs*r_;
  float mwi = A0.y + fs*i_;
  float ap = sqrtf(p_*p_ + q_*q_ + EPSF);
  float fp = (ap/(maxp+EPSF))/(ap+EPSF);
  float mpr = fp*p_, mpi = fp*q_;
  float den = sqrtf(mpr*mpr + mpi*mpi + EPSF);
  out[o] = (mwr*mpr + mwi*mpi)/den;
}

// ---------- launch ----------

extern "C" void kernel_launch(void* const* d_in, const int* in_sizes, int n_in,
                              void* d_out, int out_size, void* d_ws, size_t ws_size,
                              hipStream_t stream){
  const float* x     = (const float*)d_in[0];
  const float* Win   = (const float*)d_in[1];
  const float* bin   = (const float*)d_in[2];
  const float* Wg    = (const float*)d_in[3];
  const float* bg    = (const float*)d_in[4];
  const float* Wt    = (const float*)d_in[5];
  const float* bt    = (const float*)d_in[6];
  const float* convw = (const float*)d_in[7];
  const float* convb = (const float*)d_in[8];
  const float* wstat = (const float*)d_in[9];
  const float* wmod  = (const float*)d_in[10];
  float* out = (float*)d_out;
  float* ws  = (float*)d_ws;

  float* xtT     = ws;                   // [FF][B]   262144
  float* xgT     = ws + 262144;          // [FF][B]   262144
  float* ctx_in  = ws + 524288;          // [B][FF]   262144
  float* ctx2T   = ws + 786432;          // [FF][B]   262144
  float* modc    = ws + 1048576;         // [B][16][512] 262144
  float* msr     = ws + 1310720;         // [B][NPIX] 2097152
  float* msi     = ws + 3407872;
  float* ppr     = ws + 5505024;
  float* ppi     = ws + 7602176;
  float* red     = ws + 9699328;         // max_s[32], max_p[32]
  float* magpart = ws + 9699392;         // [32][32]
  float* invmag  = ws + 9700416;         // [32]

  k_init    <<<1,    64,  0, stream>>>(red);
  k_gemm1   <<<2048, 256, 0, stream>>>(x, Win, bin, Wg, bg, xtT, xgT);
  k_normgate<<<128,  256, 0, stream>>>(xtT, xgT, ctx_in);
  k_gemm2   <<<1024, 256, 0, stream>>>(ctx_in, Wt, bt, ctx2T);
  k_norm512 <<<512,  256, 0, stream>>>(ctx2T, modc);
  k_pixel1  <<<512,  256, 0, stream>>>(modc, convw, convb, wmod, wstat,
                                       msr, msi, ppr, ppi, red);
  k_magsum  <<<1024, 256, 0, stream>>>(msr, msi, red, magpart);
  k_finalize<<<1,    64,  0, stream>>>(magpart, invmag);
  k_final   <<<8192, 256, 0, stream>>>(msr, msi, ppr, ppi, wstat, red, invmag, out);
}

// Round 2
// 212.878 us; speedup vs baseline: 6.8560x; 6.8560x over previous
//
#include <hip/hip_runtime.h>
#include <cstddef>

#define NB   32
#define CTXD 1024
#define FFD  8192
#define HD   256
#define WD   256
#define NPIX 65536
#define EPSF 1e-12f

// ---------- helpers ----------

__device__ __forceinline__ float ftanh(float x){
  float ax = fabsf(x);
  float e  = __expf(2.0f*ax);
  float r  = 1.0f - 2.0f*__builtin_amdgcn_rcpf(e + 1.0f);
  return copysignf(r, x);
}

__device__ __forceinline__ void block_reduce4(float& a, float& b, float& c, float& d){
  for (int off = 32; off > 0; off >>= 1){
    a += __shfl_down(a, off); b += __shfl_down(b, off);
    c += __shfl_down(c, off); d += __shfl_down(d, off);
  }
  __shared__ float lds[16];
  int wid = threadIdx.x >> 6, lane = threadIdx.x & 63;
  if (lane == 0){ lds[wid*4+0]=a; lds[wid*4+1]=b; lds[wid*4+2]=c; lds[wid*4+3]=d; }
  __syncthreads();
  a = (lds[0]+lds[4])+(lds[8]+lds[12]);
  b = (lds[1]+lds[5])+(lds[9]+lds[13]);
  c = (lds[2]+lds[6])+(lds[10]+lds[14]);
  d = (lds[3]+lds[7])+(lds[11]+lds[15]);
}

// ---------- kernels ----------

__global__ __launch_bounds__(64) void k_init(float* __restrict__ red){
  if (threadIdx.x < 64) red[threadIdx.x] = 0.0f;
}

// Tiled GEMM: C[n][b] += sum_k W[n][k]*A[b][k], partials per k-chunk.
// Block tile: 128 features x 32 batches, BK=32. grid = (N/128, S).
// Cp layout: [S][N][32].
__global__ __launch_bounds__(256) void k_gemm_tiled(
    const float* __restrict__ A, const float* __restrict__ W,
    float* __restrict__ Cp, int K, int kchunk){
  __shared__ float As[32][36];
  __shared__ float Bs[128][36];
  int n0 = blockIdx.x * 128;
  int kc = blockIdx.y;
  int N  = gridDim.x * 128;
  int t  = threadIdx.x;
  int rf = t >> 3, cb = t & 7;         // rf: 0..31, cb: 0..7
  float acc[4][4] = {{0.f}};           // [feat j][batch i]
  int kend = kchunk >> 5;
  for (int kit = 0; kit < kend; ++kit){
    int kbase = kc*kchunk + kit*32;
    // stage A tile: 32 batches x 32 k (row rf = batch)
    {
      float4 v = *(const float4*)(A + (size_t)rf*K + kbase + cb*4);
      As[rf][cb*4+0]=v.x; As[rf][cb*4+1]=v.y; As[rf][cb*4+2]=v.z; As[rf][cb*4+3]=v.w;
    }
    // stage B tile: 128 feature rows x 32 k
    #pragma unroll
    for (int p = 0; p < 4; ++p){
      int row = (t>>3) + p*32;
      float4 v = *(const float4*)(W + (size_t)(n0+row)*K + kbase + cb*4);
      Bs[row][cb*4+0]=v.x; Bs[row][cb*4+1]=v.y; Bs[row][cb*4+2]=v.z; Bs[row][cb*4+3]=v.w;
    }
    __syncthreads();
    #pragma unroll
    for (int kk = 0; kk < 32; kk += 4){
      float4 av[4], wv[4];
      #pragma unroll
      for (int i = 0; i < 4; ++i) av[i] = *(const float4*)(&As[cb + 8*i][kk]);
      #pragma unroll
      for (int j = 0; j < 4; ++j) wv[j] = *(const float4*)(&Bs[rf + 32*j][kk]);
      #pragma unroll
      for (int j = 0; j < 4; ++j)
        #pragma unroll
        for (int i = 0; i < 4; ++i)
          acc[j][i] += wv[j].x*av[i].x + wv[j].y*av[i].y
                     + wv[j].z*av[i].z + wv[j].w*av[i].w;
    }
    __syncthreads();
  }
  #pragma unroll
  for (int j = 0; j < 4; ++j)
    #pragma unroll
    for (int i = 0; i < 4; ++i){
      int f = n0 + rf + 32*j;
      Cp[((size_t)kc*N + f)*32 + cb + 8*i] = acc[j][i];
    }
}

// outT[f*32+b] = bias[f] + sum_s Cp[s][f][b]
__global__ __launch_bounds__(256) void k_gemm_reduce(
    const float* __restrict__ Cp, const float* __restrict__ bias,
    float* __restrict__ outT, int S, int N){
  int g = blockIdx.x*256 + threadIdx.x;
  int f = g >> 5;
  float s = bias[f];
  for (int sI = 0; sI < S; ++sI) s += Cp[(size_t)sI*N*32 + g];
  outT[g] = s;
}

// norm over 2048-groups (ddof=1) for xt,xg; ctx_in = nt * tanh(ng)   [B][FF]
__global__ __launch_bounds__(256) void k_normgate(
    const float* __restrict__ xtT, const float* __restrict__ xgT, float* __restrict__ ctx_in){
  int b = blockIdx.x >> 2, g = blockIdx.x & 3;
  int t = threadIdx.x;
  int fbase = g*2048;
  float vt[8], vg[8];
  float st=0.f, sst=0.f, sg=0.f, ssg=0.f;
  #pragma unroll
  for (int i = 0; i < 8; ++i){
    int f = fbase + i*256 + t;
    float a = xtT[f*NB + b];
    float c = xgT[f*NB + b];
    vt[i]=a; vg[i]=c;
    st += a; sst += a*a; sg += c; ssg += c*c;
  }
  block_reduce4(st, sst, sg, ssg);
  float mt = st * (1.0f/2048.0f);
  float it = rsqrtf((sst - st*mt) * (1.0f/2047.0f) + EPSF);
  float mg = sg * (1.0f/2048.0f);
  float ig = rsqrtf((ssg - sg*mg) * (1.0f/2047.0f) + EPSF);
  #pragma unroll
  for (int i = 0; i < 8; ++i){
    int f = fbase + i*256 + t;
    float nt = (vt[i]-mt)*it;
    float ng = (vg[i]-mg)*ig;
    ctx_in[b*FFD + f] = nt * ftanh(ng);
  }
}

// norm over 512-groups (ddof=1) -> modc [B][16][512]
__global__ __launch_bounds__(256) void k_norm512(
    const float* __restrict__ ctx2T, float* __restrict__ modc){
  int b = blockIdx.x >> 4, kr = blockIdx.x & 15;
  int t = threadIdx.x;
  int base = kr*512;
  float v0 = ctx2T[(base + t      )*NB + b];
  float v1 = ctx2T[(base + 256 + t)*NB + b];
  float s = v0+v1, ss = v0*v0 + v1*v1, d0=0.f, d1=0.f;
  block_reduce4(s, ss, d0, d1);
  float m   = s * (1.0f/512.0f);
  float inv = rsqrtf((ss - s*m) * (1.0f/511.0f) + EPSF);
  modc[b*FFD + base + t      ] = (v0-m)*inv;
  modc[b*FFD + base + 256 + t] = (v1-m)*inv;
}

// pixel pass 1
__global__ __launch_bounds__(256) void k_pixel1(
    const float* __restrict__ modc,
    const float* __restrict__ convw, const float* __restrict__ convb,
    const float* __restrict__ wmod, const float* __restrict__ wstat,
    float* __restrict__ msr, float* __restrict__ msi,
    float* __restrict__ ppr, float* __restrict__ ppi,
    float* __restrict__ red){
  int b = blockIdx.x >> 4, chunk = blockIdx.x & 15;
  int t = threadIdx.x;
  __shared__ float lds[16*512];
  #pragma unroll
  for (int i = 0; i < 8; ++i){
    float4 v = *(const float4*)(modc + (size_t)b*FFD + (i*256 + t)*4);
    *(float4*)(lds + (i*256 + t)*4) = v;
  }
  float cw0 = convw[0]+convw[4]+convw[8]+convw[12];
  float cw1 = convw[1]+convw[5]+convw[9]+convw[13];
  float cw2 = convw[2]+convw[6]+convw[10]+convw[14];
  float cw3 = convw[3]+convw[7]+convw[11]+convw[15];
  float cb  = convb[0]+convb[1]+convb[2]+convb[3];
  __syncthreads();
  int w = t;
  float mxs = 0.f, mxp = 0.f;
  for (int it = 0; it < 16; ++it){
    int h = chunk*16 + it;
    int pix = h*WD + w;
    float sk[4];
    #pragma unroll
    for (int k = 0; k < 4; ++k){
      float acc = 0.f;
      #pragma unroll
      for (int r = 0; r < 4; ++r){
        int kr = k*4 + r;
        float u  = lds[kr*512 + h];
        float vv = lds[kr*512 + 256 + w];
        float tt = ftanh(u*vv);
        float cwr = (r==0)?cw0:(r==1)?cw1:(r==2)?cw2:cw3;
        acc += (k==0) ? cwr*tt : tt;
      }
      sk[k] = acc;
    }
    sk[0] += cb;
    float m0 = sk[0]*wmod[0*NPIX+pix];
    float m1 = sk[1]*wmod[1*NPIX+pix];
    float m2 = sk[2]*wmod[2*NPIX+pix];
    float m3 = sk[3]*wmod[3*NPIX+pix];
    float2 A1 = *(const float2*)(wstat + (size_t)(NPIX + pix)*2);
    float r_ = A1.x*m0 - A1.y*m1;
    float i_ = A1.x*m1 - A1.y*m0;
    size_t o = (size_t)b*NPIX + pix;
    msr[o]=r_; msi[o]=i_; ppr[o]=m2; ppi[o]=m3;
    float as = sqrtf(r_*r_ + i_*i_ + EPSF);
    float ap = sqrtf(m2*m2 + m3*m3 + EPSF);
    mxs = fmaxf(mxs, as); mxp = fmaxf(mxp, ap);
  }
  for (int off = 32; off > 0; off >>= 1){
    mxs = fmaxf(mxs, __shfl_down(mxs, off));
    mxp = fmaxf(mxp, __shfl_down(mxp, off));
  }
  __shared__ float lred[8];
  int wid = t >> 6, lane = t & 63;
  if (lane == 0){ lred[wid] = mxs; lred[4+wid] = mxp; }
  __syncthreads();
  if (t == 0){
    float a = fmaxf(fmaxf(lred[0],lred[1]), fmaxf(lred[2],lred[3]));
    float p = fmaxf(fmaxf(lred[4],lred[5]), fmaxf(lred[6],lred[7]));
    atomicMax((int*)&red[b],    __float_as_int(a));
    atomicMax((int*)&red[32+b], __float_as_int(p));
  }
}

// pixel pass 2: deterministic partial sums of |mod_scaled|
__global__ __launch_bounds__(256) void k_magsum(
    const float* __restrict__ msr, const float* __restrict__ msi,
    const float* __restrict__ red, float* __restrict__ magpart){
  int b = blockIdx.x >> 5, chunk = blockIdx.x & 31;
  int t = threadIdx.x;
  float maxs = red[b];
  float sum = 0.f;
  #pragma unroll
  for (int i = 0; i < 8; ++i){
    int pix = chunk*2048 + i*256 + t;
    size_t o = (size_t)b*NPIX + pix;
    float r_ = msr[o], i_ = msi[o];
    float sq = r_*r_ + i_*i_;
    float as = sqrtf(sq + EPSF);
    float hs = as/(maxs + EPSF);
    float tt = hs/(as + EPSF);
    sum += sqrtf(tt*tt*sq + EPSF);
  }
  for (int off = 32; off > 0; off >>= 1) sum += __shfl_down(sum, off);
  __shared__ float lr[4];
  int wid = t >> 6, lane = t & 63;
  if (lane == 0) lr[wid] = sum;
  __syncthreads();
  if (t == 0) magpart[b*32 + chunk] = (lr[0]+lr[1])+(lr[2]+lr[3]);
}

__global__ __launch_bounds__(64) void k_finalize(
    const float* __restrict__ magpart, float* __restrict__ invmag){
  int b = threadIdx.x;
  if (b < 32){
    float s = 0.f;
    for (int i = 0; i < 32; ++i) s += magpart[b*32 + i];
    invmag[b] = 1.0f / sqrtf(s*(1.0f/65536.0f) + EPSF);
  }
}

__global__ __launch_bounds__(256) void k_final(
    const float* __restrict__ msr, const float* __restrict__ msi,
    const float* __restrict__ ppr, const float* __restrict__ ppi,
    const float* __restrict__ wstat, const float* __restrict__ red,
    const float* __restrict__ invmag, float* __restrict__ out){
  int g = blockIdx.x*256 + threadIdx.x;
  int b = g >> 16, pix = g & (NPIX-1);
  size_t o = (size_t)b*NPIX + pix;
  float maxs = red[b], maxp = red[32+b], im = invmag[b];
  float r_ = msr[o], i_ = msi[o], p_ = ppr[o], q_ = ppi[o];
  float as = sqrtf(r_*r_ + i_*i_ + EPSF);
  float fs = (as/(maxs+EPSF))/(as+EPSF)*im;
  float2 A0 = *(const float2*)(wstat + (size_t)pix*2);
  float mwr = A0.x + fs*r_;
  float mwi = A0.y + fs*i_;
  float ap = sqrtf(p_*p_ + q_*q_ + EPSF);
  float fp = (ap/(maxp+EPSF))/(ap+EPSF);
  float mpr = fp*p_, mpi = fp*q_;
  float den = sqrtf(mpr*mpr + mpi*mpi + EPSF);
  out[o] = (mwr*mpr + mwi*mpi)/den;
}

// ---------- launch ----------

extern "C" void kernel_launch(void* const* d_in, const int* in_sizes, int n_in,
                              void* d_out, int out_size, void* d_ws, size_t ws_size,
                              hipStream_t stream){
  const float* x     = (const float*)d_in[0];
  const float* Win   = (const float*)d_in[1];
  const float* bin   = (const float*)d_in[2];
  const float* Wg    = (const float*)d_in[3];
  const float* bg    = (const float*)d_in[4];
  const float* Wt    = (const float*)d_in[5];
  const float* bt    = (const float*)d_in[6];
  const float* convw = (const float*)d_in[7];
  const float* convb = (const float*)d_in[8];
  const float* wstat = (const float*)d_in[9];
  const float* wmod  = (const float*)d_in[10];
  float* out = (float*)d_out;
  float* ws  = (float*)d_ws;

  float* xtT     = ws;                   // [FF][B]   262144
  float* xgT     = ws + 262144;          // [FF][B]   262144
  float* ctx_in  = ws + 524288;          // [B][FF]   262144
  float* ctx2T   = ws + 786432;          // [FF][B]   262144
  float* modc    = ws + 1048576;         // [B][16][512] 262144
  float* msr     = ws + 1310720;         // [B][NPIX] 2097152
  float* msi     = ws + 3407872;
  float* ppr     = ws + 5505024;
  float* ppi     = ws + 7602176;
  float* red     = ws + 9699328;
  float* magpart = ws + 9699392;
  float* invmag  = ws + 9700416;

  // GEMM partial buffers alias the pixel-plane regions (free until k_pixel1):
  float* Cp2  = msr;   // 8 * 8192 * 32 = 2M floats (msr+msi regions, 8MB... uses msr fully + part of msi)
  float* Cp1a = ppr;   // 4 * 8192 * 32 = 1M floats
  float* Cp1b = ppi;   // 1M floats

  k_init<<<1, 64, 0, stream>>>(red);

  // GEMM1: xt, xg (N=8192, K=1024, S=4, kchunk=256)
  k_gemm_tiled<<<dim3(64,4), 256, 0, stream>>>(x, Win, Cp1a, CTXD, 256);
  k_gemm_tiled<<<dim3(64,4), 256, 0, stream>>>(x, Wg,  Cp1b, CTXD, 256);
  k_gemm_reduce<<<1024, 256, 0, stream>>>(Cp1a, bin, xtT, 4, FFD);
  k_gemm_reduce<<<1024, 256, 0, stream>>>(Cp1b, bg,  xgT, 4, FFD);

  k_normgate<<<128, 256, 0, stream>>>(xtT, xgT, ctx_in);

  // GEMM2: ctx2 (N=8192, K=8192, S=8, kchunk=1024)
  k_gemm_tiled<<<dim3(64,8), 256, 0, stream>>>(ctx_in, Wt, Cp2, FFD, 1024);
  k_gemm_reduce<<<1024, 256, 0, stream>>>(Cp2, bt, ctx2T, 8, FFD);

  k_norm512<<<512, 256, 0, stream>>>(ctx2T, modc);
  k_pixel1<<<512, 256, 0, stream>>>(modc, convw, convb, wmod, wstat,
                                    msr, msi, ppr, ppi, red);
  k_magsum<<<1024, 256, 0, stream>>>(msr, msi, red, magpart);
  k_finalize<<<1, 64, 0, stream>>>(magpart, invmag);
  k_final<<<8192, 256, 0, stream>>>(msr, msi, ppr, ppi, wstat, red, invmag, out);
}